// Round 2
// baseline (1369.752 us; speedup 1.0000x reference)
//
#include <hip/hip_runtime.h>

#define B_DIM 4
#define S_DIM 4096
#define D_DIM 256
#define L_DIM 8921
#define L_PAD 8960  // 70 * 128

typedef _Float16 f16x8 __attribute__((ext_vector_type(8)));
typedef _Float16 f16x4 __attribute__((ext_vector_type(4)));
typedef float    f32x4 __attribute__((ext_vector_type(4)));

// async 16B global -> LDS (direct, no VGPR round trip)
__device__ __forceinline__ void cp16(_Float16* lds, const _Float16* g) {
  __builtin_amdgcn_global_load_lds(
      (const __attribute__((address_space(1))) unsigned int*)g,
      (__attribute__((address_space(3))) unsigned int*)lds, 16, 0, 0);
}

// ---------------------------------------------------------------------------
// K0a: split x (fp32) -> x_hi, x_lo (f16), elementwise. a = hi + lo to ~2^-22.
// ---------------------------------------------------------------------------
__global__ __launch_bounds__(256) void k_split_x(const float* __restrict__ x,
                                                 _Float16* __restrict__ xh,
                                                 _Float16* __restrict__ xl) {
  const size_t i = ((size_t)blockIdx.x * 256 + threadIdx.x) * 4;
  float4 v = *(const float4*)(x + i);
  f16x4 h, l;
  h.x = (_Float16)v.x; l.x = (_Float16)(v.x - (float)h.x);
  h.y = (_Float16)v.y; l.y = (_Float16)(v.y - (float)h.y);
  h.z = (_Float16)v.z; l.z = (_Float16)(v.z - (float)h.z);
  h.w = (_Float16)v.w; l.w = (_Float16)(v.w - (float)h.w);
  *(f16x4*)(xh + i) = h;
  *(f16x4*)(xl + i) = l;
}

// ---------------------------------------------------------------------------
// K0b: split U (fp32) -> U_hi, U_lo (f16), ZERO-padded to L_PAD rows so that
// k_scores' unmasked global_load_lds staging stays in-bounds and clean.
// ---------------------------------------------------------------------------
__global__ __launch_bounds__(256) void k_split_u(const float* __restrict__ U,
                                                 _Float16* __restrict__ uh,
                                                 _Float16* __restrict__ ul) {
  const size_t i = ((size_t)blockIdx.x * 256 + threadIdx.x) * 4;
  if (i >= (size_t)L_PAD * D_DIM) return;
  float4 v = make_float4(0.f, 0.f, 0.f, 0.f);
  if (i < (size_t)L_DIM * D_DIM) v = *(const float4*)(U + i);
  f16x4 h, l;
  h.x = (_Float16)v.x; l.x = (_Float16)(v.x - (float)h.x);
  h.y = (_Float16)v.y; l.y = (_Float16)(v.y - (float)h.y);
  h.z = (_Float16)v.z; l.z = (_Float16)(v.z - (float)h.z);
  h.w = (_Float16)v.w; l.w = (_Float16)(v.w - (float)h.w);
  *(f16x4*)(uh + i) = h;
  *(f16x4*)(ul + i) = l;
}

// ---------------------------------------------------------------------------
// K0c: xT_hi[b][d][s] = f16(x[b][s][d])  (tiled 32x32 transpose via LDS)
// ---------------------------------------------------------------------------
__global__ __launch_bounds__(256) void k_transpose(const float* __restrict__ x,
                                                   _Float16* __restrict__ xT) {
  __shared__ _Float16 t[32][33];
  const int s0 = blockIdx.x * 32, d0 = blockIdx.y * 32, b = blockIdx.z;
  const float* xb = x + (size_t)b * S_DIM * D_DIM;
  const int r = threadIdx.x >> 5, c = threadIdx.x & 31;
#pragma unroll
  for (int p = 0; p < 4; ++p) {
    const int row = r + p * 8;
    t[row][c] = (_Float16)xb[(size_t)(s0 + row) * D_DIM + d0 + c];
  }
  __syncthreads();
  _Float16* xtb = xT + (size_t)b * D_DIM * S_DIM;
#pragma unroll
  for (int p = 0; p < 4; ++p) {
    const int row = r + p * 8;
    xtb[(size_t)(d0 + row) * S_DIM + s0 + c] = t[c][row];
  }
}

// ---------------------------------------------------------------------------
// K1: scores[b][l][s] = sum_d U[l,d] x[b,s,d]  (fp32 via split-f16 3-product)
// 128x128 tile, BK=32. Staging via global_load_lds(16B) with XOR chunk
// swizzle (both-sides). Fused per-row softmax partials {max, sum_exp}.
// grid: (S/128, L_PAD/128, B), block 256 (4 waves, 2x2, each 64x64).
// ---------------------------------------------------------------------------
__global__ __launch_bounds__(256) void k_scores(const _Float16* __restrict__ Uh,
                                                const _Float16* __restrict__ Ul,
                                                const _Float16* __restrict__ Xh,
                                                const _Float16* __restrict__ Xl,
                                                float* __restrict__ scores,
                                                float2* __restrict__ part) {
  const int s0 = blockIdx.x * 128;
  const int l0 = blockIdx.y * 128;
  const int b  = blockIdx.z;

  __shared__ __attribute__((aligned(16))) _Float16 Ah[128 * 32];
  __shared__ __attribute__((aligned(16))) _Float16 Al[128 * 32];
  __shared__ __attribute__((aligned(16))) _Float16 Bh[128 * 32];
  __shared__ __attribute__((aligned(16))) _Float16 Bl[128 * 32];

  const int tid = threadIdx.x;
  const int wave = tid >> 6, lane = tid & 63;
  const int wm = wave & 1, wn = wave >> 1;

  const _Float16* Xbh = Xh + (size_t)b * S_DIM * D_DIM;
  const _Float16* Xbl = Xl + (size_t)b * S_DIM * D_DIM;

  const int srow = tid >> 2;
  const int csrc = ((tid & 3) ^ ((tid >> 3) & 3)) * 8;  // pre-swizzled source
  const size_t urow0 = (size_t)(l0 + srow) * D_DIM + csrc;
  const size_t urow1 = urow0 + (size_t)64 * D_DIM;
  const size_t xrow0 = (size_t)(s0 + srow) * D_DIM + csrc;
  const size_t xrow1 = xrow0 + (size_t)64 * D_DIM;
  const int ldso = tid * 8;

  const int frow = lane & 15;
  const int ck = ((lane >> 4) ^ ((frow >> 1) & 3)) * 8;

  f32x4 acc[4][4] = {};

  for (int k0 = 0; k0 < D_DIM; k0 += 32) {
    cp16(Ah + ldso,        Uh + urow0 + k0);
    cp16(Ah + 2048 + ldso, Uh + urow1 + k0);
    cp16(Al + ldso,        Ul + urow0 + k0);
    cp16(Al + 2048 + ldso, Ul + urow1 + k0);
    cp16(Bh + ldso,        Xbh + xrow0 + k0);
    cp16(Bh + 2048 + ldso, Xbh + xrow1 + k0);
    cp16(Bl + ldso,        Xbl + xrow0 + k0);
    cp16(Bl + 2048 + ldso, Xbl + xrow1 + k0);
    __syncthreads();

    f16x8 ah[4], al[4], bh[4], bl[4];
#pragma unroll
    for (int i = 0; i < 4; ++i) {
      const int ra = (wm * 64 + i * 16 + frow) * 32 + ck;
      const int rb = (wn * 64 + i * 16 + frow) * 32 + ck;
      ah[i] = *(const f16x8*)(Ah + ra);
      al[i] = *(const f16x8*)(Al + ra);
      bh[i] = *(const f16x8*)(Bh + rb);
      bl[i] = *(const f16x8*)(Bl + rb);
    }
#pragma unroll
    for (int i = 0; i < 4; ++i)
#pragma unroll
      for (int j = 0; j < 4; ++j) {
        acc[i][j] = __builtin_amdgcn_mfma_f32_16x16x32_f16(ah[i], bh[j], acc[i][j], 0, 0, 0);
        acc[i][j] = __builtin_amdgcn_mfma_f32_16x16x32_f16(ah[i], bl[j], acc[i][j], 0, 0, 0);
        acc[i][j] = __builtin_amdgcn_mfma_f32_16x16x32_f16(al[i], bh[j], acc[i][j], 0, 0, 0);
      }
    __syncthreads();
  }

  // ---- C write (raw scores, fp32) ----
  float* sc = scores + (size_t)b * L_DIM * S_DIM;
  const int hi = lane >> 4;
#pragma unroll
  for (int i = 0; i < 4; ++i)
#pragma unroll
    for (int j = 0; j < 4; ++j) {
      const int col = s0 + wn * 64 + j * 16 + (lane & 15);
#pragma unroll
      for (int r = 0; r < 4; ++r) {
        const int row = l0 + wm * 64 + i * 16 + hi * 4 + r;
        if (row < L_DIM) sc[(size_t)row * S_DIM + col] = acc[i][j][r];
      }
    }

  // ---- fused softmax partials over this block's 128 s-columns ----
  float* redm = (float*)Ah;  // [2][2][64] : [wm][wn][row64]
  float* reds = redm + 256;
#pragma unroll
  for (int i = 0; i < 4; ++i)
#pragma unroll
    for (int r = 0; r < 4; ++r) {
      float m = fmaxf(fmaxf(acc[i][0][r], acc[i][1][r]),
                      fmaxf(acc[i][2][r], acc[i][3][r]));
      m = fmaxf(m, __shfl_xor(m, 1));
      m = fmaxf(m, __shfl_xor(m, 2));
      m = fmaxf(m, __shfl_xor(m, 4));
      m = fmaxf(m, __shfl_xor(m, 8));
      float s = __expf(acc[i][0][r] - m) + __expf(acc[i][1][r] - m) +
                __expf(acc[i][2][r] - m) + __expf(acc[i][3][r] - m);
      s += __shfl_xor(s, 1);
      s += __shfl_xor(s, 2);
      s += __shfl_xor(s, 4);
      s += __shfl_xor(s, 8);
      if ((lane & 15) == 0) {
        const int row64 = i * 16 + hi * 4 + r;
        redm[(wm * 2 + wn) * 64 + row64] = m;
        reds[(wm * 2 + wn) * 64 + row64] = s;
      }
    }
  __syncthreads();
  if (tid < 128) {
    const int wmm = tid >> 6, r64 = tid & 63;
    const float m0 = redm[(wmm * 2 + 0) * 64 + r64];
    const float m1 = redm[(wmm * 2 + 1) * 64 + r64];
    const float s0v = reds[(wmm * 2 + 0) * 64 + r64];
    const float s1v = reds[(wmm * 2 + 1) * 64 + r64];
    const float m = fmaxf(m0, m1);
    const float s = s0v * __expf(m0 - m) + s1v * __expf(m1 - m);
    const int l = l0 + tid;
    if (l < L_DIM)
      part[((size_t)blockIdx.x * B_DIM + b) * L_PAD + l] = make_float2(m, s);
  }
}

// ---------------------------------------------------------------------------
// K2: reduce 32 per-s-tile partials -> stats[b][l] = {rowmax, 1/sum}
// ---------------------------------------------------------------------------
__global__ __launch_bounds__(256) void k_sreduce(const float2* __restrict__ part,
                                                 float* __restrict__ stats) {
  const int idx = blockIdx.x * 256 + threadIdx.x;
  if (idx >= B_DIM * L_DIM) return;
  const int b = idx / L_DIM;
  const int l = idx - b * L_DIM;
  float2 v[32];
#pragma unroll
  for (int t = 0; t < 32; ++t) v[t] = part[((size_t)t * B_DIM + b) * L_PAD + l];
  float m = v[0].x;
#pragma unroll
  for (int t = 1; t < 32; ++t) m = fmaxf(m, v[t].x);
  float s = 0.f;
#pragma unroll
  for (int t = 0; t < 32; ++t) s += v[t].y * __expf(v[t].x - m);
  stats[2 * (size_t)idx]     = m;
  stats[2 * (size_t)idx + 1] = 1.0f / s;
}

// ---------------------------------------------------------------------------
// K3: alpha = softmax(scores) in-place (fp32); out = alpha @ x via f16 MFMA.
// v3: L-tile 32; DOUBLE-BUFFERED LDS, ONE barrier per s-tile; next-tile loads
// issued POST-barrier so they stay in flight across the MFMA phase (hipcc
// drains vmcnt(0) at each barrier -> post-barrier issue == counted vmcnt).
// B-tile via global_load_lds with pre-swizzled source; 32-f16 stride + XOR
// chunk swizzle (the k_scores-proven layout; reverts round-1's 40-f16 pad).
// grid: (ceil(L/32), B), block 256 (4 waves along D, each 32x64).
// ---------------------------------------------------------------------------
__global__ __launch_bounds__(256) void k_out(const _Float16* __restrict__ XT,
                                             const float* __restrict__ stats,
                                             float* __restrict__ alpha,
                                             float* __restrict__ out) {
  const int l0 = blockIdx.x * 32;
  const int b  = blockIdx.y;
  const int tid = threadIdx.x;
  const int wave = tid >> 6, lane = tid & 63;

  __shared__ __attribute__((aligned(16))) _Float16 Aa[2][32 * 32];
  __shared__ __attribute__((aligned(16))) _Float16 Bb[2][256 * 32];
  __shared__ float sm[32], sr[32];

  if (tid < 32) {
    const int l = l0 + tid;
    float m = 0.f, r = 0.f;
    if (l < L_DIM) {
      const float* st = stats + ((size_t)b * L_DIM + l) * 2;
      m = st[0];
      r = st[1];
    }
    sm[tid] = m;
    sr[tid] = r;
  }
  __syncthreads();

  f32x4 acc[2][4] = {};
  float* al_base = alpha + (size_t)b * L_DIM * S_DIM;
  const _Float16* xt = XT + (size_t)b * D_DIM * S_DIM;

  // A staging: tid -> row tid>>3 (0..31), 8B slot tid&7; XOR chunk swizzle.
  const int arow = tid >> 3, a8 = tid & 7;
  const int aoff = a8 * 4;  // logical f32 offset within the 32-col tile
  const float m_r = sm[arow], r_r = sr[arow];  // r_r==0 masks rows >= L_DIM
  const int l_a = l0 + arow;
  const int aphys = arow * 32 + (((a8 >> 1) ^ ((arow >> 1) & 3)) * 8) + (a8 & 1) * 4;

  // B staging via global_load_lds: tid stages 16B at linear dest tid*8 f16
  // (+p*2048); global source s-offset pre-swizzled (same involution).
  const int brow = tid >> 2;
  const int bsrc = ((tid & 3) ^ ((tid >> 3) & 3)) * 8;  // f16 offset in s
  const int bdst = tid * 8;

  // fragment read swizzle
  const int frow = lane & 15;
  const int ck = ((lane >> 4) ^ ((frow >> 1) & 3)) * 8;

  float* ap0 = (l_a < L_DIM) ? (al_base + (size_t)l_a * S_DIM + aoff) : nullptr;

  // prologue: stage tile 0
#pragma unroll
  for (int p = 0; p < 4; ++p)
    cp16(&Bb[0][p * 2048 + bdst], xt + (size_t)(brow + p * 64) * S_DIM + bsrc);
  float4 va = make_float4(0.f, 0.f, 0.f, 0.f);
  if (ap0) va = *(const float4*)ap0;

  const int NT = S_DIM / 32;  // 128
  for (int t = 0; t < NT; ++t) {
    const int cur = t & 1;
    // exp tile t in regs, stage A into LDS (r_r==0 zeroes masked rows)
    float4 e;
    e.x = __expf(va.x - m_r) * r_r;
    e.y = __expf(va.y - m_r) * r_r;
    e.z = __expf(va.z - m_r) * r_r;
    e.w = __expf(va.w - m_r) * r_r;
    f16x4 pk;
    pk.x = (_Float16)e.x;
    pk.y = (_Float16)e.y;
    pk.z = (_Float16)e.z;
    pk.w = (_Float16)e.w;
    *(f16x4*)(&Aa[cur][aphys]) = pk;
    __syncthreads();  // drains tile-t B gloads (issued last iter) + A writes

    // post-barrier: alpha writeback t; issue tile t+1 loads (in flight
    // across this iteration's MFMA phase, drained at the NEXT barrier).
    if (ap0) *(float4*)(ap0 + (size_t)t * 32) = e;
    if (t + 1 < NT) {
      const int s1 = (t + 1) * 32;
#pragma unroll
      for (int p = 0; p < 4; ++p)
        cp16(&Bb[cur ^ 1][p * 2048 + bdst],
             xt + (size_t)(brow + p * 64) * S_DIM + s1 + bsrc);
      if (ap0) va = *(const float4*)(ap0 + (size_t)(t + 1) * 32);
    }

    // compute on buffer cur
    f16x8 af0 = *(const f16x8*)(&Aa[cur][frow * 32 + ck]);
    f16x8 af1 = *(const f16x8*)(&Aa[cur][(16 + frow) * 32 + ck]);
    f16x8 bf[4];
#pragma unroll
    for (int j = 0; j < 4; ++j)
      bf[j] = *(const f16x8*)(&Bb[cur][(wave * 64 + j * 16 + frow) * 32 + ck]);
#pragma unroll
    for (int j = 0; j < 4; ++j) {
      acc[0][j] = __builtin_amdgcn_mfma_f32_16x16x32_f16(af0, bf[j], acc[0][j], 0, 0, 0);
      acc[1][j] = __builtin_amdgcn_mfma_f32_16x16x32_f16(af1, bf[j], acc[1][j], 0, 0, 0);
    }
  }

  float* ob = out + (size_t)b * L_DIM * D_DIM;
#pragma unroll
  for (int i = 0; i < 2; ++i)
#pragma unroll
    for (int j = 0; j < 4; ++j) {
      const int d = wave * 64 + j * 16 + (lane & 15);
#pragma unroll
      for (int r = 0; r < 4; ++r) {
        const int l = l0 + i * 16 + (lane >> 4) * 4 + r;
        if (l < L_DIM) ob[(size_t)l * D_DIM + d] = acc[i][j][r];
      }
    }
}

// ---------------------------------------------------------------------------
extern "C" void kernel_launch(void* const* d_in, const int* in_sizes, int n_in,
                              void* d_out, int out_size, void* d_ws, size_t ws_size,
                              hipStream_t stream) {
  const float* x = (const float*)d_in[0];
  const float* U = (const float*)d_in[1];
  float* out   = (float*)d_out;
  float* alpha = out + (size_t)B_DIM * L_DIM * D_DIM;  // raw scores, then alpha

  const size_t NX  = (size_t)B_DIM * S_DIM * D_DIM;  // 4,194,304
  const size_t NUP = (size_t)L_PAD * D_DIM;          // 2,293,760

  // workspace (~43 MB): x_hi, x_lo, xT, U_hi(pad), U_lo(pad), stats, partials
  char* w = (char*)d_ws;
  _Float16* xh = (_Float16*)w; w += NX * 2;
  _Float16* xl = (_Float16*)w; w += NX * 2;
  _Float16* xT = (_Float16*)w; w += NX * 2;
  _Float16* uh = (_Float16*)w; w += NUP * 2;
  _Float16* ul = (_Float16*)w; w += NUP * 2;
  float* stats = (float*)w;    w += (size_t)B_DIM * L_DIM * 2 * sizeof(float);
  float2* part = (float2*)w;   // [32][B][L_PAD]

  k_split_x<<<dim3((unsigned)(NX / 1024)), 256, 0, stream>>>(x, xh, xl);
  k_split_u<<<dim3((unsigned)(NUP / 1024)), 256, 0, stream>>>(U, uh, ul);
  k_transpose<<<dim3(S_DIM / 32, D_DIM / 32, B_DIM), 256, 0, stream>>>(x, xT);
  k_scores<<<dim3(S_DIM / 128, L_PAD / 128, B_DIM), 256, 0, stream>>>(
      uh, ul, xh, xl, alpha, part);
  k_sreduce<<<dim3((B_DIM * L_DIM + 255) / 256), 256, 0, stream>>>(part, stats);
  k_out<<<dim3((L_DIM + 31) / 32, B_DIM), 256, 0, stream>>>(xT, stats, alpha, out);
}

// Round 3
// 1254.143 us; speedup vs baseline: 1.0922x; 1.0922x over previous
//
#include <hip/hip_runtime.h>

#define B_DIM 4
#define S_DIM 4096
#define D_DIM 256
#define L_DIM 8921
#define L_PAD 8960  // 70 * 128

typedef _Float16 f16x8 __attribute__((ext_vector_type(8)));
typedef _Float16 f16x4 __attribute__((ext_vector_type(4)));
typedef float    f32x4 __attribute__((ext_vector_type(4)));

// async 16B global -> LDS (direct, no VGPR round trip)
__device__ __forceinline__ void cp16(_Float16* lds, const _Float16* g) {
  __builtin_amdgcn_global_load_lds(
      (const __attribute__((address_space(1))) unsigned int*)g,
      (__attribute__((address_space(3))) unsigned int*)lds, 16, 0, 0);
}

// ---------------------------------------------------------------------------
// K0a: split x (fp32) -> x_hi, x_lo (f16), elementwise. a = hi + lo to ~2^-22.
// ---------------------------------------------------------------------------
__global__ __launch_bounds__(256) void k_split_x(const float* __restrict__ x,
                                                 _Float16* __restrict__ xh,
                                                 _Float16* __restrict__ xl) {
  const size_t i = ((size_t)blockIdx.x * 256 + threadIdx.x) * 4;
  float4 v = *(const float4*)(x + i);
  f16x4 h, l;
  h.x = (_Float16)v.x; l.x = (_Float16)(v.x - (float)h.x);
  h.y = (_Float16)v.y; l.y = (_Float16)(v.y - (float)h.y);
  h.z = (_Float16)v.z; l.z = (_Float16)(v.z - (float)h.z);
  h.w = (_Float16)v.w; l.w = (_Float16)(v.w - (float)h.w);
  *(f16x4*)(xh + i) = h;
  *(f16x4*)(xl + i) = l;
}

// ---------------------------------------------------------------------------
// K0b: split U (fp32) -> U_hi, U_lo (f16), ZERO-padded to L_PAD rows.
// ---------------------------------------------------------------------------
__global__ __launch_bounds__(256) void k_split_u(const float* __restrict__ U,
                                                 _Float16* __restrict__ uh,
                                                 _Float16* __restrict__ ul) {
  const size_t i = ((size_t)blockIdx.x * 256 + threadIdx.x) * 4;
  if (i >= (size_t)L_PAD * D_DIM) return;
  float4 v = make_float4(0.f, 0.f, 0.f, 0.f);
  if (i < (size_t)L_DIM * D_DIM) v = *(const float4*)(U + i);
  f16x4 h, l;
  h.x = (_Float16)v.x; l.x = (_Float16)(v.x - (float)h.x);
  h.y = (_Float16)v.y; l.y = (_Float16)(v.y - (float)h.y);
  h.z = (_Float16)v.z; l.z = (_Float16)(v.z - (float)h.z);
  h.w = (_Float16)v.w; l.w = (_Float16)(v.w - (float)h.w);
  *(f16x4*)(uh + i) = h;
  *(f16x4*)(ul + i) = l;
}

// ---------------------------------------------------------------------------
// K0c: xT[b][d][s] = f16(x[b][s][d])  (tiled 32x32 transpose via LDS)
// ---------------------------------------------------------------------------
__global__ __launch_bounds__(256) void k_transpose(const float* __restrict__ x,
                                                   _Float16* __restrict__ xT) {
  __shared__ _Float16 t[32][33];
  const int s0 = blockIdx.x * 32, d0 = blockIdx.y * 32, b = blockIdx.z;
  const float* xb = x + (size_t)b * S_DIM * D_DIM;
  const int r = threadIdx.x >> 5, c = threadIdx.x & 31;
#pragma unroll
  for (int p = 0; p < 4; ++p) {
    const int row = r + p * 8;
    t[row][c] = (_Float16)xb[(size_t)(s0 + row) * D_DIM + d0 + c];
  }
  __syncthreads();
  _Float16* xtb = xT + (size_t)b * D_DIM * S_DIM;
#pragma unroll
  for (int p = 0; p < 4; ++p) {
    const int row = r + p * 8;
    xtb[(size_t)(d0 + row) * S_DIM + s0 + c] = t[c][row];
  }
}

// ---------------------------------------------------------------------------
// K1: scores[b][l][s] = sum_d U[l,d] x[b,s,d]  (fp32 via split-f16 3-product)
// 128x128 tile, BK=32, gload_lds(16B) + XOR chunk swizzle (both sides).
// v3: FULL LDS DOUBLE-BUFFER (64 KB), ONE barrier per k-step, next-step
// staging issued post-barrier -> in flight across the 48-MFMA (~930cy)
// compute phase, drained at the next barrier. Fused softmax partials.
// grid: (S/128, L_PAD/128, B), block 256 (4 waves, 2x2, each 64x64).
// ---------------------------------------------------------------------------
__global__ __launch_bounds__(256) void k_scores(const _Float16* __restrict__ Uh,
                                                const _Float16* __restrict__ Ul,
                                                const _Float16* __restrict__ Xh,
                                                const _Float16* __restrict__ Xl,
                                                float* __restrict__ scores,
                                                float2* __restrict__ part) {
  const int s0 = blockIdx.x * 128;
  const int l0 = blockIdx.y * 128;
  const int b  = blockIdx.z;

  __shared__ __attribute__((aligned(16))) _Float16 Ah[2][128 * 32];
  __shared__ __attribute__((aligned(16))) _Float16 Al[2][128 * 32];
  __shared__ __attribute__((aligned(16))) _Float16 Bh[2][128 * 32];
  __shared__ __attribute__((aligned(16))) _Float16 Bl[2][128 * 32];

  const int tid = threadIdx.x;
  const int wave = tid >> 6, lane = tid & 63;
  const int wm = wave & 1, wn = wave >> 1;

  const _Float16* Xbh = Xh + (size_t)b * S_DIM * D_DIM;
  const _Float16* Xbl = Xl + (size_t)b * S_DIM * D_DIM;

  const int srow = tid >> 2;
  const int csrc = ((tid & 3) ^ ((tid >> 3) & 3)) * 8;  // pre-swizzled source
  const size_t urow0 = (size_t)(l0 + srow) * D_DIM + csrc;
  const size_t urow1 = urow0 + (size_t)64 * D_DIM;
  const size_t xrow0 = (size_t)(s0 + srow) * D_DIM + csrc;
  const size_t xrow1 = xrow0 + (size_t)64 * D_DIM;
  const int ldso = tid * 8;

  const int frow = lane & 15;
  const int ck = ((lane >> 4) ^ ((frow >> 1) & 3)) * 8;

  f32x4 acc[4][4] = {};

  auto stage = [&](int nb, int k0) {
    cp16(&Ah[nb][ldso],        Uh + urow0 + k0);
    cp16(&Ah[nb][2048 + ldso], Uh + urow1 + k0);
    cp16(&Al[nb][ldso],        Ul + urow0 + k0);
    cp16(&Al[nb][2048 + ldso], Ul + urow1 + k0);
    cp16(&Bh[nb][ldso],        Xbh + xrow0 + k0);
    cp16(&Bh[nb][2048 + ldso], Xbh + xrow1 + k0);
    cp16(&Bl[nb][ldso],        Xbl + xrow0 + k0);
    cp16(&Bl[nb][2048 + ldso], Xbl + xrow1 + k0);
  };

  stage(0, 0);  // prologue: tile 0 in flight

  const int NK = D_DIM / 32;  // 8
  for (int ks = 0; ks < NK; ++ks) {
    const int cur = ks & 1;
    __syncthreads();  // drains stage(cur); protects buffers (reads of cur^1
                      // finished before this barrier last iteration)
    if (ks + 1 < NK) stage(cur ^ 1, (ks + 1) * 32);  // hidden under MFMAs

    f16x8 ah[4], al[4], bh[4], bl[4];
#pragma unroll
    for (int i = 0; i < 4; ++i) {
      const int ra = (wm * 64 + i * 16 + frow) * 32 + ck;
      const int rb = (wn * 64 + i * 16 + frow) * 32 + ck;
      ah[i] = *(const f16x8*)(&Ah[cur][ra]);
      al[i] = *(const f16x8*)(&Al[cur][ra]);
      bh[i] = *(const f16x8*)(&Bh[cur][rb]);
      bl[i] = *(const f16x8*)(&Bl[cur][rb]);
    }
#pragma unroll
    for (int i = 0; i < 4; ++i)
#pragma unroll
      for (int j = 0; j < 4; ++j) {
        acc[i][j] = __builtin_amdgcn_mfma_f32_16x16x32_f16(ah[i], bh[j], acc[i][j], 0, 0, 0);
        acc[i][j] = __builtin_amdgcn_mfma_f32_16x16x32_f16(ah[i], bl[j], acc[i][j], 0, 0, 0);
        acc[i][j] = __builtin_amdgcn_mfma_f32_16x16x32_f16(al[i], bh[j], acc[i][j], 0, 0, 0);
      }
  }

  // ---- C write (raw scores, fp32) ----
  float* sc = scores + (size_t)b * L_DIM * S_DIM;
  const int hi = lane >> 4;
#pragma unroll
  for (int i = 0; i < 4; ++i)
#pragma unroll
    for (int j = 0; j < 4; ++j) {
      const int col = s0 + wn * 64 + j * 16 + (lane & 15);
#pragma unroll
      for (int r = 0; r < 4; ++r) {
        const int row = l0 + wm * 64 + i * 16 + hi * 4 + r;
        if (row < L_DIM) sc[(size_t)row * S_DIM + col] = acc[i][j][r];
      }
    }

  // ---- fused softmax partials over this block's 128 s-columns ----
  // Ah[0] is dead (last compute read buffer 1); reuse as reduction scratch.
  float* redm = (float*)&Ah[0][0];  // [2][2][64] : [wm][wn][row64]
  float* reds = redm + 256;
#pragma unroll
  for (int i = 0; i < 4; ++i)
#pragma unroll
    for (int r = 0; r < 4; ++r) {
      float m = fmaxf(fmaxf(acc[i][0][r], acc[i][1][r]),
                      fmaxf(acc[i][2][r], acc[i][3][r]));
      m = fmaxf(m, __shfl_xor(m, 1));
      m = fmaxf(m, __shfl_xor(m, 2));
      m = fmaxf(m, __shfl_xor(m, 4));
      m = fmaxf(m, __shfl_xor(m, 8));
      float s = __expf(acc[i][0][r] - m) + __expf(acc[i][1][r] - m) +
                __expf(acc[i][2][r] - m) + __expf(acc[i][3][r] - m);
      s += __shfl_xor(s, 1);
      s += __shfl_xor(s, 2);
      s += __shfl_xor(s, 4);
      s += __shfl_xor(s, 8);
      if ((lane & 15) == 0) {
        const int row64 = i * 16 + hi * 4 + r;
        redm[(wm * 2 + wn) * 64 + row64] = m;
        reds[(wm * 2 + wn) * 64 + row64] = s;
      }
    }
  __syncthreads();
  if (tid < 128) {
    const int wmm = tid >> 6, r64 = tid & 63;
    const float m0 = redm[(wmm * 2 + 0) * 64 + r64];
    const float m1 = redm[(wmm * 2 + 1) * 64 + r64];
    const float s0v = reds[(wmm * 2 + 0) * 64 + r64];
    const float s1v = reds[(wmm * 2 + 1) * 64 + r64];
    const float m = fmaxf(m0, m1);
    const float s = s0v * __expf(m0 - m) + s1v * __expf(m1 - m);
    const int l = l0 + tid;
    if (l < L_DIM)
      part[((size_t)blockIdx.x * B_DIM + b) * L_PAD + l] = make_float2(m, s);
  }
}

// ---------------------------------------------------------------------------
// K2: reduce 32 per-s-tile partials -> stats[b][l] = {rowmax, 1/sum}
// ---------------------------------------------------------------------------
__global__ __launch_bounds__(256) void k_sreduce(const float2* __restrict__ part,
                                                 float* __restrict__ stats) {
  const int idx = blockIdx.x * 256 + threadIdx.x;
  if (idx >= B_DIM * L_DIM) return;
  const int b = idx / L_DIM;
  const int l = idx - b * L_DIM;
  float2 v[32];
#pragma unroll
  for (int t = 0; t < 32; ++t) v[t] = part[((size_t)t * B_DIM + b) * L_PAD + l];
  float m = v[0].x;
#pragma unroll
  for (int t = 1; t < 32; ++t) m = fmaxf(m, v[t].x);
  float s = 0.f;
#pragma unroll
  for (int t = 0; t < 32; ++t) s += v[t].y * __expf(v[t].x - m);
  stats[2 * (size_t)idx]     = m;
  stats[2 * (size_t)idx + 1] = 1.0f / s;
}

// ---------------------------------------------------------------------------
// K3a: alpha finalize, pure streaming: alpha = exp(raw - m) * r, in place.
// NO barriers, NO LDS -> store acks never synchronously drained.
// grid: (S/1024, L_DIM, B), block 256, one float4 per thread.
// ---------------------------------------------------------------------------
__global__ __launch_bounds__(256) void k_alpha(const float* __restrict__ stats,
                                               float* __restrict__ alpha) {
  const int l = blockIdx.y, b = blockIdx.z;
  const float* st = stats + ((size_t)b * L_DIM + l) * 2;
  const float m = st[0], r = st[1];
  float4* p = (float4*)(alpha + ((size_t)b * L_DIM + l) * S_DIM) +
              blockIdx.x * 256 + threadIdx.x;
  float4 v = *p;
  v.x = __expf(v.x - m) * r;
  v.y = __expf(v.y - m) * r;
  v.z = __expf(v.z - m) * r;
  v.w = __expf(v.w - m) * r;
  *p = v;
}

// ---------------------------------------------------------------------------
// K3b: out[b][l][d] = sum_s alpha[b][l][s] * x[b][s][d]   (clean NT GEMM)
// BM=64 (l) x BN=256 (full D: alpha read exactly once) x BK=64 (s).
// A: final alpha f32 -> reg -> cvt f16 -> XOR-swizzled ds_write.
// B: xT f16 via global_load_lds(16B), pre-swizzled source.
// No global stores in the k-loop; barriers drain staging only.
// grid: (ceil(L/64), B), block 256 (4 waves along D, each 64x64).
// ---------------------------------------------------------------------------
__global__ __launch_bounds__(256) void k_out(const _Float16* __restrict__ XT,
                                             const float* __restrict__ alpha,
                                             float* __restrict__ out) {
  const int l0 = blockIdx.x * 64;
  const int b  = blockIdx.y;
  const int tid = threadIdx.x;
  const int wave = tid >> 6, lane = tid & 63;

  __shared__ __attribute__((aligned(16))) _Float16 Aa[64 * 64];
  __shared__ __attribute__((aligned(16))) _Float16 Bb[256 * 64];

  const _Float16* xt = XT + (size_t)b * D_DIM * S_DIM;
  const float* al = alpha + (size_t)b * L_DIM * S_DIM;

  // A staging: row = tid>>2 (64 rows), two 8-f16 chunks c0, c0+1.
  const int ar  = tid >> 2;
  const int ac0 = (tid & 3) * 2;
  const int l_a = l0 + ar;
  const bool amask = l_a < L_DIM;
  const float* arow = al + (size_t)l_a * S_DIM;
  const int apx0 = ar * 64 + ((ac0)     ^ (ar & 7)) * 8;
  const int apx1 = ar * 64 + ((ac0 + 1) ^ (ar & 7)) * 8;

  // B staging: 8 passes, row = (tid>>3)+p*32, linear dst, pre-swz source.
  const int br   = tid >> 3;
  const int bsrc = ((tid & 7) ^ (br & 7)) * 8;
  const int bdst = tid * 8;

  const int frow = lane & 15, hi = lane >> 4;

  f32x4 acc[4][4] = {};

  for (int ks = 0; ks < S_DIM / 64; ++ks) {
    const int s0 = ks * 64;
    // issue async B staging first (16B direct-to-LDS x8)
#pragma unroll
    for (int p = 0; p < 8; ++p)
      cp16(Bb + p * 2048 + bdst,
           xt + (size_t)(br + p * 32) * S_DIM + s0 + bsrc);
    // A: 16 f32 -> f16, swizzled LDS write (latency overlaps cp16 issue)
    float4 v0 = make_float4(0.f, 0.f, 0.f, 0.f), v1 = v0, v2 = v0, v3 = v0;
    if (amask) {
      const float* ap = arow + s0 + ac0 * 8;
      v0 = *(const float4*)(ap);
      v1 = *(const float4*)(ap + 4);
      v2 = *(const float4*)(ap + 8);
      v3 = *(const float4*)(ap + 12);
    }
    f16x8 w0, w1;
    w0[0] = (_Float16)v0.x; w0[1] = (_Float16)v0.y;
    w0[2] = (_Float16)v0.z; w0[3] = (_Float16)v0.w;
    w0[4] = (_Float16)v1.x; w0[5] = (_Float16)v1.y;
    w0[6] = (_Float16)v1.z; w0[7] = (_Float16)v1.w;
    w1[0] = (_Float16)v2.x; w1[1] = (_Float16)v2.y;
    w1[2] = (_Float16)v2.z; w1[3] = (_Float16)v2.w;
    w1[4] = (_Float16)v3.x; w1[5] = (_Float16)v3.y;
    w1[6] = (_Float16)v3.z; w1[7] = (_Float16)v3.w;
    *(f16x8*)(Aa + apx0) = w0;
    *(f16x8*)(Aa + apx1) = w1;
    __syncthreads();  // drain staging

#pragma unroll
    for (int kh = 0; kh < 2; ++kh) {
      const int pck = ((kh * 4 + hi) ^ (frow & 7)) * 8;
      f16x8 af[4], bf[4];
#pragma unroll
      for (int i = 0; i < 4; ++i)
        af[i] = *(const f16x8*)(Aa + (i * 16 + frow) * 64 + pck);
#pragma unroll
      for (int j = 0; j < 4; ++j)
        bf[j] = *(const f16x8*)(Bb + (wave * 64 + j * 16 + frow) * 64 + pck);
#pragma unroll
      for (int i = 0; i < 4; ++i)
#pragma unroll
        for (int j = 0; j < 4; ++j)
          acc[i][j] = __builtin_amdgcn_mfma_f32_16x16x32_f16(af[i], bf[j], acc[i][j], 0, 0, 0);
    }
    __syncthreads();  // protect LDS before next staging
  }

  float* ob = out + (size_t)b * L_DIM * D_DIM;
#pragma unroll
  for (int i = 0; i < 4; ++i)
#pragma unroll
    for (int j = 0; j < 4; ++j) {
      const int d = wave * 64 + j * 16 + (lane & 15);
#pragma unroll
      for (int r = 0; r < 4; ++r) {
        const int l = l0 + i * 16 + (lane >> 4) * 4 + r;
        if (l < L_DIM) ob[(size_t)l * D_DIM + d] = acc[i][j][r];
      }
    }
}

// ---------------------------------------------------------------------------
extern "C" void kernel_launch(void* const* d_in, const int* in_sizes, int n_in,
                              void* d_out, int out_size, void* d_ws, size_t ws_size,
                              hipStream_t stream) {
  const float* x = (const float*)d_in[0];
  const float* U = (const float*)d_in[1];
  float* out   = (float*)d_out;
  float* alpha = out + (size_t)B_DIM * L_DIM * D_DIM;  // raw scores, then alpha

  const size_t NX  = (size_t)B_DIM * S_DIM * D_DIM;  // 4,194,304
  const size_t NUP = (size_t)L_PAD * D_DIM;          // 2,293,760

  // workspace (~43 MB): x_hi, x_lo, xT, U_hi(pad), U_lo(pad), stats, partials
  char* w = (char*)d_ws;
  _Float16* xh = (_Float16*)w; w += NX * 2;
  _Float16* xl = (_Float16*)w; w += NX * 2;
  _Float16* xT = (_Float16*)w; w += NX * 2;
  _Float16* uh = (_Float16*)w; w += NUP * 2;
  _Float16* ul = (_Float16*)w; w += NUP * 2;
  float* stats = (float*)w;    w += (size_t)B_DIM * L_DIM * 2 * sizeof(float);
  float2* part = (float2*)w;   // [32][B][L_PAD]

  k_split_x<<<dim3((unsigned)(NX / 1024)), 256, 0, stream>>>(x, xh, xl);
  k_split_u<<<dim3((unsigned)(NUP / 1024)), 256, 0, stream>>>(U, uh, ul);
  k_transpose<<<dim3(S_DIM / 32, D_DIM / 32, B_DIM), 256, 0, stream>>>(x, xT);
  k_scores<<<dim3(S_DIM / 128, L_PAD / 128, B_DIM), 256, 0, stream>>>(
      uh, ul, xh, xl, alpha, part);
  k_sreduce<<<dim3((B_DIM * L_DIM + 255) / 256), 256, 0, stream>>>(part, stats);
  k_alpha<<<dim3(S_DIM / 1024, L_DIM, B_DIM), 256, 0, stream>>>(stats, alpha);
  k_out<<<dim3((L_DIM + 63) / 64, B_DIM), 256, 0, stream>>>(xT, alpha, out);
}